// Round 3
// baseline (117.168 us; speedup 1.0000x reference)
//
#include <hip/hip_runtime.h>
#include <hip/hip_bf16.h>

#define NB 64
#define NC 256
#define NL 2048
#define NH 8
#define KW 3
#define LP (NL - KW + 1)  // 2046
#define NCHUNK 4
#define CPC (NC / NCHUNK)  // 64 channels per chunk
#define CSTRIDE ((size_t)NB * NH * NL)  // part chunk stride in floats

typedef float v4f __attribute__((ext_vector_type(4)));

// monotonic float->uint key: order(u) == order(x)
__device__ __forceinline__ unsigned fkey(float x) {
  unsigned b = __float_as_uint(x);
  return (b & 0x80000000u) ? ~b : (b | 0x80000000u);
}

// Kernel 1: valid conv1d partial sums over 64-channel chunks.
// Grid (LP/256, NB, NCHUNK); c-loop unrolled x4 -> 12 loads in flight.
__global__ __launch_bounds__(256) void conv_partial(
    const float* __restrict__ src, const float* __restrict__ conv_w,
    float* __restrict__ part) {
  const int l = blockIdx.x * 256 + threadIdx.x;
  const int b = blockIdx.y;
  const int cc = blockIdx.z;
  if (l >= LP) return;
  float acc[NH];
#pragma unroll
  for (int h = 0; h < NH; ++h) acc[h] = 0.f;
  const int c0 = cc * CPC;
  const float* sp = src + ((size_t)b * NC + c0) * NL + l;
  for (int c = 0; c < CPC; c += 4) {
    float a0 = sp[0], a1 = sp[1], a2 = sp[2];
    float b0 = sp[NL], b1 = sp[NL + 1], b2 = sp[NL + 2];
    float c0v = sp[2 * NL], c1v = sp[2 * NL + 1], c2v = sp[2 * NL + 2];
    float d0 = sp[3 * NL], d1 = sp[3 * NL + 1], d2 = sp[3 * NL + 2];
    sp += 4 * NL;
#pragma unroll
    for (int h = 0; h < NH; ++h) {
      const float* w = conv_w + ((h * NC + c0 + c) * KW);  // uniform -> s_load
      acc[h] = fmaf(a0, w[0], acc[h]);
      acc[h] = fmaf(a1, w[1], acc[h]);
      acc[h] = fmaf(a2, w[2], acc[h]);
      acc[h] = fmaf(b0, w[3], acc[h]);
      acc[h] = fmaf(b1, w[4], acc[h]);
      acc[h] = fmaf(b2, w[5], acc[h]);
      acc[h] = fmaf(c0v, w[6], acc[h]);
      acc[h] = fmaf(c1v, w[7], acc[h]);
      acc[h] = fmaf(c2v, w[8], acc[h]);
      acc[h] = fmaf(d0, w[9], acc[h]);
      acc[h] = fmaf(d1, w[10], acc[h]);
      acc[h] = fmaf(d2, w[11], acc[h]);
    }
  }
#pragma unroll
  for (int h = 0; h < NH; ++h)
    part[((size_t)cc * NB * NH + blockIdx.y * NH + h) * NL + l] = acc[h];
}

// Kernel 2: ONE WAVE per (b,h) row, register-resident (32 vals/lane).
// Sum partials (+bias), BN normalize, exact radix-select of k-th largest
// (stable ties like lax.top_k), sigmoid mask, 3-tap box sum via shfl,
// write cw*M into the xi row. Only LDS: 256-bin histogram.
__global__ __launch_bounds__(64) void select_wave(
    const float* __restrict__ part, float* __restrict__ xi,
    const float* __restrict__ conv_b, const float* __restrict__ bn_gamma,
    const float* __restrict__ bn_beta, const float* __restrict__ comb_w,
    const int* __restrict__ kptr) {
  const int lane = threadIdx.x;  // 0..63
  const int bh = blockIdx.x;
  const int h = bh & (NH - 1);
  __shared__ int hist[256];

  const float cb = conv_b[h];
  const float* p0 = part + (size_t)bh * NL;
  float xs[32];
  float s1 = 0.f, s2 = 0.f;
#pragma unroll
  for (int j = 0; j < 32; ++j) {
    const int l = j * 64 + lane;
    const bool valid = l < LP;  // folds to true for j<31
    float v = 0.f;
    if (valid) {
      v = ((p0[l] + p0[l + CSTRIDE]) + (p0[l + 2 * CSTRIDE] + p0[l + 3 * CSTRIDE])) + cb;
      s1 += v;
      s2 += v * v;
    }
    xs[j] = v;
  }
  // wave reduce stats
#pragma unroll
  for (int off = 32; off > 0; off >>= 1) {
    s1 += __shfl_down(s1, off);
    s2 += __shfl_down(s2, off);
  }
  s1 = __shfl(s1, 0);
  s2 = __shfl(s2, 0);
  const float mu = s1 / (float)LP;
  const float var = s2 / (float)LP - mu * mu;
  const float inv = rsqrtf(var + 1e-5f);
  const float sc = bn_gamma[h] * inv;
  const float sh = bn_beta[h] - mu * sc;
#pragma unroll
  for (int j = 0; j < 32; ++j) {
    const int l = j * 64 + lane;
    xs[j] = (l < LP) ? fmaf(xs[j], sc, sh) : -__builtin_inff();
  }

  // exact radix select of the k-th largest key (4x 8-bit passes)
  const int ktot = kptr[0];
  int kk = ktot;
  unsigned prefix = 0, pm = 0;
#pragma unroll
  for (int pass = 0; pass < 4; ++pass) {
    const int shift = 24 - 8 * pass;
    hist[lane] = 0; hist[lane + 64] = 0; hist[lane + 128] = 0; hist[lane + 192] = 0;
    __syncthreads();
#pragma unroll
    for (int j = 0; j < 32; ++j) {
      const int l = j * 64 + lane;
      if (l < LP) {
        unsigned u = fkey(xs[j]);
        if ((u & pm) == prefix) atomicAdd(&hist[(u >> shift) & 255], 1);
      }
    }
    __syncthreads();
    // wave suffix-scan over 256 bins, 4 bins/lane (bins ascend with lane)
    const int h0 = hist[lane * 4 + 0], h1 = hist[lane * 4 + 1];
    const int h2 = hist[lane * 4 + 2], h3 = hist[lane * 4 + 3];
    const int g = h0 + h1 + h2 + h3;
    int sfx = g;
#pragma unroll
    for (int off = 1; off < 64; off <<= 1) {
      int o = __shfl(sfx, (lane + off) & 63);
      if (lane + off < 64) sfx += o;
    }
    const int A = sfx - g;  // strictly-higher groups
    const int s3 = A + h3, s2i = s3 + h2, s1i = s2i + h1, s0i = s1i + h0;
    int mybin = -1, mykk = 0;
    if (s0i >= kk && s0i - h0 < kk) { mybin = lane * 4 + 0; mykk = kk - (s0i - h0); }
    if (s1i >= kk && s1i - h1 < kk) { mybin = lane * 4 + 1; mykk = kk - (s1i - h1); }
    if (s2i >= kk && s2i - h2 < kk) { mybin = lane * 4 + 2; mykk = kk - (s2i - h2); }
    if (s3  >= kk && s3  - h3 < kk) { mybin = lane * 4 + 3; mykk = kk - (s3 - h3); }
    unsigned long long mb = __ballot(mybin >= 0);
    const int srcl = __ffsll((long long)mb) - 1;
    const int binp = __shfl(mybin, srcl);
    kk = __shfl(mykk, srcl);
    prefix |= ((unsigned)binp) << shift;
    pm |= 255u << shift;
    __syncthreads();
  }
  const unsigned T = prefix;

  // counts for tie handling
  int cgt = 0, ceq = 0;
#pragma unroll
  for (int j = 0; j < 32; ++j) {
    const int l = j * 64 + lane;
    if (l < LP) {
      unsigned u = fkey(xs[j]);
      cgt += (u > T);
      ceq += (u == T);
    }
  }
#pragma unroll
  for (int off = 32; off > 0; off >>= 1) {
    cgt += __shfl_down(cgt, off);
    ceq += __shfl_down(ceq, off);
  }
  cgt = __shfl(cgt, 0);
  ceq = __shfl(ceq, 0);
  const int need_eq = ktot - cgt;

  // mask + sigmoid in-place (xs becomes m)
  if (ceq == need_eq) {
#pragma unroll
    for (int j = 0; j < 32; ++j) {
      const int l = j * 64 + lane;
      float x = xs[j];
      bool sel = (l < LP) && (fkey(x) >= T);
      xs[j] = sel ? 1.f / (1.f + __expf(-x)) : 0.f;
    }
  } else {  // rare ties: lowest-index-first like lax.top_k
    int rem = need_eq;
#pragma unroll
    for (int j = 0; j < 32; ++j) {
      const int l = j * 64 + lane;
      float x = xs[j];
      unsigned u = fkey(x);
      bool iseq = (l < LP) && (u == T);
      unsigned long long mb = __ballot(iseq);
      unsigned long long below = mb & ((1ull << lane) - 1ull);
      bool sel = ((l < LP) && (u > T)) ||
                 (iseq && ((int)__popcll((long long)below) < rem));
      rem -= (int)__popcll((long long)mb);
      if (rem < 0) rem = 0;
      xs[j] = sel ? 1.f / (1.f + __expf(-x)) : 0.f;
    }
  }

  // 3-tap box sum via shuffles; write this head's gate contribution
  const float cw = comb_w[h] * (1.0f / (float)KW);
  float* row = xi + (size_t)bh * NL;
  float mprev = 0.f;  // m[j-1] register (all lanes hold their own)
#pragma unroll
  for (int j = 0; j < 32; ++j) {
    const float cur = xs[j];
    float up1 = __shfl_up(cur, 1);
    float up2 = __shfl_up(cur, 2);
    const float p63 = __shfl(mprev, 63);
    const float p62 = __shfl(mprev, 62);
    if (lane == 0) { up1 = (j > 0) ? p63 : 0.f; up2 = (j > 0) ? p62 : 0.f; }
    if (lane == 1) { up2 = (j > 0) ? p63 : 0.f; }
    row[j * 64 + lane] = cw * ((cur + up1) + up2);
    mprev = cur;
  }
}

// Kernel 3: gate[b,l] = sum_h contribution[b,h,l], float4.
__global__ __launch_bounds__(256) void gate_combine(
    const float* __restrict__ xi, float* __restrict__ gate) {
  const int idx = blockIdx.x * 256 + threadIdx.x;  // over NB*NL/4
  const int b = idx >> 9;           // NL/4 = 512 float4 per b
  const int l4 = idx & 511;
  const v4f* p = (const v4f*)(xi + (size_t)b * NH * NL) + l4;
  v4f s = p[0];
#pragma unroll
  for (int h = 1; h < NH; ++h) s += p[(size_t)h * (NL / 4)];
  ((v4f*)gate)[idx] = s;
}

// Kernel 4: out = src * gate[b,l] + comb_b; nontemporal stores so the 134 MB
// of output writes don't evict src from L3 (src is re-read here after conv).
__global__ __launch_bounds__(256) void scale_kernel(
    const float* __restrict__ src, const float* __restrict__ gate,
    const float* __restrict__ comb_b, float* __restrict__ out) {
  const size_t total = (size_t)NB * NC * NL / 4;
  const float cb = comb_b[0];
  for (size_t idx = (size_t)blockIdx.x * blockDim.x + threadIdx.x; idx < total;
       idx += (size_t)gridDim.x * blockDim.x) {
    const size_t e = idx * 4;
    const int l = (int)(e & (NL - 1));
    const int b = (int)(e >> 19);  // C*L = 2^19
    v4f sv = ((const v4f*)src)[idx];
    v4f gv = *(const v4f*)(gate + (size_t)b * NL + l);
    v4f ov;
    ov.x = fmaf(sv.x, gv.x, cb);
    ov.y = fmaf(sv.y, gv.y, cb);
    ov.z = fmaf(sv.z, gv.z, cb);
    ov.w = fmaf(sv.w, gv.w, cb);
    __builtin_nontemporal_store(ov, (v4f*)out + idx);
  }
}

extern "C" void kernel_launch(void* const* d_in, const int* in_sizes, int n_in,
                              void* d_out, int out_size, void* d_ws, size_t ws_size,
                              hipStream_t stream) {
  const float* src = (const float*)d_in[0];
  const float* conv_w = (const float*)d_in[1];
  const float* conv_b = (const float*)d_in[2];
  const float* bn_gamma = (const float*)d_in[3];
  const float* bn_beta = (const float*)d_in[4];
  const float* comb_w = (const float*)d_in[5];
  const float* comb_b = (const float*)d_in[6];
  const int* kptr = (const int*)d_in[7];
  float* out = (float*)d_out;

  float* xi = (float*)d_ws;                 // NB*NH*NL floats (4 MB)
  float* gate = xi + (size_t)NB * NH * NL;  // NB*NL floats (512 KB)
  float* part = out;                        // 16 MB scratch inside d_out
                                            // (fully overwritten by scale_kernel)

  conv_partial<<<dim3((LP + 255) / 256, NB, NCHUNK), 256, 0, stream>>>(src, conv_w, part);
  select_wave<<<NB * NH, 64, 0, stream>>>(part, xi, conv_b, bn_gamma, bn_beta, comb_w, kptr);
  gate_combine<<<(NB * NL) / (4 * 256), 256, 0, stream>>>(xi, gate);
  scale_kernel<<<2048, 256, 0, stream>>>(src, gate, comb_b, out);
}

// Round 4
// 100.349 us; speedup vs baseline: 1.1676x; 1.1676x over previous
//
#include <hip/hip_runtime.h>
#include <hip/hip_bf16.h>

#define NB 64
#define NC 256
#define NL 2048
#define NH 8
#define KW 3
#define LP (NL - KW + 1)  // 2046
#define NCHUNK 8
#define CPC (NC / NCHUNK)  // 32 channels per chunk

typedef float v4f __attribute__((ext_vector_type(4)));

// monotonic float->uint key: order(u) == order(x)
__device__ __forceinline__ unsigned fkey(float x) {
  unsigned b = __float_as_uint(x);
  return (b & 0x80000000u) ? ~b : (b | 0x80000000u);
}

// Kernel 1: conv1d partial sums. Each thread: 4 consecutive l outputs x 8
// heads from ONE float4 load per channel (+shuffle halo). 96 FMA per 16B
// load -> latency hides under VALU. Grid (2, NB, NCHUNK).
// part layout: [(b*NH+h)*NCHUNK + cc][l] so the reducer reads contiguous rows.
__global__ __launch_bounds__(256) void conv_partial(
    const float* __restrict__ src, const float* __restrict__ conv_w,
    float* __restrict__ part) {
  const int t = threadIdx.x;
  const int lane = t & 63;
  const int l0 = blockIdx.x * 1024 + t * 4;
  const int b = blockIdx.y;
  const int cc = blockIdx.z;
  const int c0 = cc * CPC;

  float acc[NH][4];
#pragma unroll
  for (int h = 0; h < NH; ++h)
#pragma unroll
    for (int j = 0; j < 4; ++j) acc[h][j] = 0.f;

  const float* sp = src + ((size_t)b * NC + c0) * NL + l0;
  const bool tail = (lane == 63) && (l0 + 5 < NL);
#pragma unroll 2
  for (int c = 0; c < CPC; ++c) {
    v4f v = *(const v4f*)sp;
    float e0 = 0.f, e1 = 0.f;
    if (tail) { e0 = sp[4]; e1 = sp[5]; }
    sp += NL;
    float n0 = __shfl_down(v.x, 1);
    float n1 = __shfl_down(v.y, 1);
    if (lane == 63) { n0 = e0; n1 = e1; }
    float s0 = v.x, s1 = v.y, s2 = v.z, s3 = v.w, s4 = n0, s5 = n1;
#pragma unroll
    for (int h = 0; h < NH; ++h) {
      const float* w = conv_w + (h * NC + c0 + c) * KW;  // uniform -> s_load
      const float w0 = w[0], w1 = w[1], w2 = w[2];
      acc[h][0] = fmaf(s0, w0, fmaf(s1, w1, fmaf(s2, w2, acc[h][0])));
      acc[h][1] = fmaf(s1, w0, fmaf(s2, w1, fmaf(s3, w2, acc[h][1])));
      acc[h][2] = fmaf(s2, w0, fmaf(s3, w1, fmaf(s4, w2, acc[h][2])));
      acc[h][3] = fmaf(s3, w0, fmaf(s4, w1, fmaf(s5, w2, acc[h][3])));
    }
  }
#pragma unroll
  for (int h = 0; h < NH; ++h) {
    float* pr = part + ((size_t)(b * NH + h) * NCHUNK + cc) * NL + l0;
    if (l0 + 3 < LP) {
      *(v4f*)pr = *(v4f*)acc[h];
    } else {
#pragma unroll
      for (int j = 0; j < 4; ++j)
        if (l0 + j < LP) pr[j] = acc[h][j];
    }
  }
}

// Kernel 1b: xi[bh][l] = sum_cc part[bh*NCHUNK+cc][l] + conv_b[h].
// Pure BW kernel with full parallelism (1024 blocks).
__global__ __launch_bounds__(256) void reduce_kernel(
    const float* __restrict__ part, const float* __restrict__ conv_b,
    float* __restrict__ xi) {
  const int idx = blockIdx.x * 256 + threadIdx.x;  // over NB*NH*NL/4
  const int bh = idx >> 9;  // NL/4 = 512 float4 per row
  const int l4 = idx & 511;
  const float cb = conv_b[bh & (NH - 1)];
  const v4f* p = (const v4f*)(part + (size_t)bh * NCHUNK * NL) + l4;
  v4f s = p[0];
#pragma unroll
  for (int k = 1; k < NCHUNK; ++k) s += p[(size_t)k * (NL / 4)];
  s += (v4f){cb, cb, cb, cb};
  ((v4f*)xi)[idx] = s;
}

// Kernel 2: ONE WAVE per (b,h) row, register-resident (32 vals/lane).
// BN normalize, exact radix-select of k-th largest (stable ties like
// lax.top_k), sigmoid mask, 3-tap box sum via shfl, write cw*M over xi row.
__global__ __launch_bounds__(64) void select_wave(
    float* __restrict__ xi, const float* __restrict__ bn_gamma,
    const float* __restrict__ bn_beta, const float* __restrict__ comb_w,
    const int* __restrict__ kptr) {
  const int lane = threadIdx.x;  // 0..63
  const int bh = blockIdx.x;
  const int h = bh & (NH - 1);
  __shared__ int hist[256];

  float* row = xi + (size_t)bh * NL;
  float xs[32];
  float s1 = 0.f, s2 = 0.f;
#pragma unroll
  for (int j = 0; j < 32; ++j) {
    const int l = j * 64 + lane;
    float v = 0.f;
    if (l < LP) {
      v = row[l];
      s1 += v;
      s2 += v * v;
    }
    xs[j] = v;
  }
#pragma unroll
  for (int off = 32; off > 0; off >>= 1) {
    s1 += __shfl_down(s1, off);
    s2 += __shfl_down(s2, off);
  }
  s1 = __shfl(s1, 0);
  s2 = __shfl(s2, 0);
  const float mu = s1 / (float)LP;
  const float var = s2 / (float)LP - mu * mu;
  const float inv = rsqrtf(var + 1e-5f);
  const float sc = bn_gamma[h] * inv;
  const float sh = bn_beta[h] - mu * sc;
#pragma unroll
  for (int j = 0; j < 32; ++j) {
    const int l = j * 64 + lane;
    xs[j] = (l < LP) ? fmaf(xs[j], sc, sh) : -__builtin_inff();
  }

  // exact radix select of the k-th largest key (4x 8-bit passes)
  const int ktot = kptr[0];
  int kk = ktot;
  unsigned prefix = 0, pm = 0;
#pragma unroll
  for (int pass = 0; pass < 4; ++pass) {
    const int shift = 24 - 8 * pass;
    hist[lane] = 0; hist[lane + 64] = 0; hist[lane + 128] = 0; hist[lane + 192] = 0;
    __syncthreads();
#pragma unroll
    for (int j = 0; j < 32; ++j) {
      const int l = j * 64 + lane;
      if (l < LP) {
        unsigned u = fkey(xs[j]);
        if ((u & pm) == prefix) atomicAdd(&hist[(u >> shift) & 255], 1);
      }
    }
    __syncthreads();
    // wave suffix-scan over 256 bins, 4 bins/lane (bins ascend with lane)
    const int h0 = hist[lane * 4 + 0], h1 = hist[lane * 4 + 1];
    const int h2 = hist[lane * 4 + 2], h3 = hist[lane * 4 + 3];
    const int g = h0 + h1 + h2 + h3;
    int sfx = g;
#pragma unroll
    for (int off = 1; off < 64; off <<= 1) {
      int o = __shfl(sfx, (lane + off) & 63);
      if (lane + off < 64) sfx += o;
    }
    const int A = sfx - g;  // strictly-higher groups
    const int s3 = A + h3, s2i = s3 + h2, s1i = s2i + h1, s0i = s1i + h0;
    int mybin = -1, mykk = 0;
    if (s0i >= kk && s0i - h0 < kk) { mybin = lane * 4 + 0; mykk = kk - (s0i - h0); }
    if (s1i >= kk && s1i - h1 < kk) { mybin = lane * 4 + 1; mykk = kk - (s1i - h1); }
    if (s2i >= kk && s2i - h2 < kk) { mybin = lane * 4 + 2; mykk = kk - (s2i - h2); }
    if (s3  >= kk && s3  - h3 < kk) { mybin = lane * 4 + 3; mykk = kk - (s3 - h3); }
    unsigned long long mb = __ballot(mybin >= 0);
    const int srcl = __ffsll((long long)mb) - 1;
    const int binp = __shfl(mybin, srcl);
    kk = __shfl(mykk, srcl);
    prefix |= ((unsigned)binp) << shift;
    pm |= 255u << shift;
    __syncthreads();
  }
  const unsigned T = prefix;

  // counts for tie handling
  int cgt = 0, ceq = 0;
#pragma unroll
  for (int j = 0; j < 32; ++j) {
    const int l = j * 64 + lane;
    if (l < LP) {
      unsigned u = fkey(xs[j]);
      cgt += (u > T);
      ceq += (u == T);
    }
  }
#pragma unroll
  for (int off = 32; off > 0; off >>= 1) {
    cgt += __shfl_down(cgt, off);
    ceq += __shfl_down(ceq, off);
  }
  cgt = __shfl(cgt, 0);
  ceq = __shfl(ceq, 0);
  const int need_eq = ktot - cgt;

  // mask + sigmoid in-place (xs becomes m)
  if (ceq == need_eq) {
#pragma unroll
    for (int j = 0; j < 32; ++j) {
      const int l = j * 64 + lane;
      float x = xs[j];
      bool sel = (l < LP) && (fkey(x) >= T);
      xs[j] = sel ? 1.f / (1.f + __expf(-x)) : 0.f;
    }
  } else {  // rare ties: lowest-index-first like lax.top_k
    int rem = need_eq;
#pragma unroll
    for (int j = 0; j < 32; ++j) {
      const int l = j * 64 + lane;
      float x = xs[j];
      unsigned u = fkey(x);
      bool iseq = (l < LP) && (u == T);
      unsigned long long mb = __ballot(iseq);
      unsigned long long below = mb & ((1ull << lane) - 1ull);
      bool sel = ((l < LP) && (u > T)) ||
                 (iseq && ((int)__popcll((long long)below) < rem));
      rem -= (int)__popcll((long long)mb);
      if (rem < 0) rem = 0;
      xs[j] = sel ? 1.f / (1.f + __expf(-x)) : 0.f;
    }
  }

  // 3-tap box sum via shuffles; write this head's gate contribution
  const float cw = comb_w[h] * (1.0f / (float)KW);
  float mprev = 0.f;
#pragma unroll
  for (int j = 0; j < 32; ++j) {
    const float cur = xs[j];
    float up1 = __shfl_up(cur, 1);
    float up2 = __shfl_up(cur, 2);
    const float p63 = __shfl(mprev, 63);
    const float p62 = __shfl(mprev, 62);
    if (lane == 0) { up1 = (j > 0) ? p63 : 0.f; up2 = (j > 0) ? p62 : 0.f; }
    if (lane == 1) { up2 = (j > 0) ? p63 : 0.f; }
    row[j * 64 + lane] = cw * ((cur + up1) + up2);
    mprev = cur;
  }
}

// Kernel 3: gate[b,l] = sum_h contribution[b,h,l], float4.
__global__ __launch_bounds__(256) void gate_combine(
    const float* __restrict__ xi, float* __restrict__ gate) {
  const int idx = blockIdx.x * 256 + threadIdx.x;  // over NB*NL/4
  const int b = idx >> 9;  // NL/4 = 512 float4 per b
  const int l4 = idx & 511;
  const v4f* p = (const v4f*)(xi + (size_t)b * NH * NL) + l4;
  v4f s = p[0];
#pragma unroll
  for (int h = 1; h < NH; ++h) s += p[(size_t)h * (NL / 4)];
  ((v4f*)gate)[idx] = s;
}

// Kernel 4: out = src * gate[b,l] + comb_b; nontemporal stores so 134 MB of
// output writes don't evict src/gate from cache.
__global__ __launch_bounds__(256) void scale_kernel(
    const float* __restrict__ src, const float* __restrict__ gate,
    const float* __restrict__ comb_b, float* __restrict__ out) {
  const size_t total = (size_t)NB * NC * NL / 4;
  const float cb = comb_b[0];
  for (size_t idx = (size_t)blockIdx.x * blockDim.x + threadIdx.x; idx < total;
       idx += (size_t)gridDim.x * blockDim.x) {
    const size_t e = idx * 4;
    const int l = (int)(e & (NL - 1));
    const int b = (int)(e >> 19);  // C*L = 2^19
    v4f sv = ((const v4f*)src)[idx];
    v4f gv = *(const v4f*)(gate + (size_t)b * NL + l);
    v4f ov;
    ov.x = fmaf(sv.x, gv.x, cb);
    ov.y = fmaf(sv.y, gv.y, cb);
    ov.z = fmaf(sv.z, gv.z, cb);
    ov.w = fmaf(sv.w, gv.w, cb);
    __builtin_nontemporal_store(ov, (v4f*)out + idx);
  }
}

extern "C" void kernel_launch(void* const* d_in, const int* in_sizes, int n_in,
                              void* d_out, int out_size, void* d_ws, size_t ws_size,
                              hipStream_t stream) {
  const float* src = (const float*)d_in[0];
  const float* conv_w = (const float*)d_in[1];
  const float* conv_b = (const float*)d_in[2];
  const float* bn_gamma = (const float*)d_in[3];
  const float* bn_beta = (const float*)d_in[4];
  const float* comb_w = (const float*)d_in[5];
  const float* comb_b = (const float*)d_in[6];
  const int* kptr = (const int*)d_in[7];
  float* out = (float*)d_out;

  float* xi = (float*)d_ws;                 // NB*NH*NL floats (4 MB)
  float* gate = xi + (size_t)NB * NH * NL;  // NB*NL floats (512 KB)
  float* part = out;                        // 32 MB scratch inside d_out
                                            // (fully overwritten by scale_kernel)

  conv_partial<<<dim3(2, NB, NCHUNK), 256, 0, stream>>>(src, conv_w, part);
  reduce_kernel<<<(NB * NH * NL) / (4 * 256), 256, 0, stream>>>(part, conv_b, xi);
  select_wave<<<NB * NH, 64, 0, stream>>>(xi, bn_gamma, bn_beta, comb_w, kptr);
  gate_combine<<<(NB * NL) / (4 * 256), 256, 0, stream>>>(xi, gate);
  scale_kernel<<<2048, 256, 0, stream>>>(src, gate, comb_b, out);
}